// Round 9
// baseline (88.890 us; speedup 1.0000x reference)
//
#include <hip/hip_runtime.h>
#include <math.h>
#include <stdint.h>

#define NM 8          // nmul
#define NPAR 12
#define TCH 128       // timesteps per LDS chunk
#define CHDW (TCH*24) // dwords per chunk buffer (24 dwords = 96B per step-row)
#define NLL 12        // 1KB global_load_lds ops per chunk (TCH*96/1024)
#define BATCH 8       // steps per LDS-read batch (TCH % BATCH == 0)

typedef __attribute__((address_space(1))) const void gv_t;
typedef __attribute__((address_space(3))) void lv_t;

__global__ __launch_bounds__(64, 1) void hbv_kernel(
    const float* __restrict__ x,      // [T, G, 3]  (prcp, tmean, pet)
    const float* __restrict__ praw,   // [1, G, 12, NM] in [0,1)
    float* __restrict__ out,          // [T, G, NM]
    int G, int T)
{
    __shared__ float lds[2][CHDW];    // 24,576 B double-buffered forcing stage

    const int lane = threadIdx.x;     // block = 1 wave = 8 g's x 8 m's
    const int b    = blockIdx.x;
    const int g0   = b << 3;
    const int gl   = lane >> 3;       // g within block
    const int m    = lane & 7;
    const int g    = g0 + gl;

    // Parameter bounds: BETA, FC, K0, K1, K2, LP, PERC, UZL, TT, CFMAX, CFR, CWH
    const float lb[NPAR] = {1.0f, 50.0f, 0.05f, 0.01f, 0.001f, 0.2f, 0.0f, 0.0f, -2.5f, 0.5f, 0.0f, 0.0f};
    const float ub[NPAR] = {6.0f, 1000.0f, 0.9f, 0.5f, 0.2f, 1.0f, 10.0f, 100.0f, 2.5f, 10.0f, 0.1f, 0.2f};

    float p[NPAR];
    const float* pr = praw + (size_t)g * (NPAR * NM) + m;
    #pragma unroll
    for (int i = 0; i < NPAR; ++i) p[i] = pr[i * NM] * (ub[i] - lb[i]) + lb[i];

    const float BETA = p[0], FC = p[1], K0 = p[2], K1 = p[3], K2 = p[4], LP = p[5],
                PERCc = p[6], UZL = p[7], TT = p[8], CFMAX = p[9], CFR = p[10], CWH = p[11];

    // --- derived loop-invariants (fma-folded) ---
    const float invLPFC     = 1.0f / (LP * FC);
    const float nCFMAX_TT   = -(CFMAX * TT);
    const float nCFRCFMAX   = -(CFR * CFMAX);
    const float CFRCFMAX_TT = (CFR * CFMAX) * TT;
    const float nBLFC       = -BETA * __builtin_amdgcn_logf(FC);  // -BETA*log2(FC)
    const float OMK0        = 1.0f - K0;
    const float K0UZL       = K0 * UZL;
    const float OMK1        = 1.0f - K1;
    const float OMK2        = 1.0f - K2;

    float SP = 0.001f, MW = 0.001f, SM = 0.001f, SUZ = 0.001f, SLZ = 0.001f;

    // --- chunk-copy geometry (all 16B-aligned: 96 = 6*16, G*12 = 48000 = 16*3000) ---
    const char* xb = (const char*)x;
    const uint32_t xstep  = (uint32_t)G * 12u;     // bytes per timestep row of x
    const uint32_t gbase  = (uint32_t)g0 * 12u;    // block's column base (16B-aligned)
    const uint32_t lin    = (uint32_t)lane * 16u;  // lane's slice of each 1KB segment
    const uint32_t r0     = lin / 96u;             // row within chunk for segment 0
    const uint32_t c0     = lin % 96u;             // col (byte) within row, in {0,16,..,80}
    const uint32_t rowmax = (uint32_t)(T - 1);

    // Issue one chunk's 12 async 1KB copies HBM -> LDS (no VGPRs held, cannot
    // be sunk by the allocator). LDS dest is wave-uniform base + lane*16,
    // global src is the matching per-lane address; rows clamp to T-1.
    #define ISSUE_CHUNK(cs_, nb_)                                              \
    {                                                                          \
        uint32_t row_ = (uint32_t)(cs_) + r0;                                  \
        uint32_t col_ = c0;                                                    \
        _Pragma("unroll")                                                      \
        for (int i_ = 0; i_ < NLL; ++i_) {                                     \
            const uint32_t rg_ = row_ < rowmax ? row_ : rowmax;                \
            const uint32_t go_ = rg_ * xstep + gbase + col_;                   \
            __builtin_amdgcn_global_load_lds((gv_t*)(xb + go_),                \
                (lv_t*)&lds[nb_][i_ * 256], 16, 0, 0);                         \
            /* advance 1024B = 10 rows + 64B within the 96B-row raster */      \
            row_ += 10u + (col_ >= 32u ? 1u : 0u);                             \
            col_  = (col_ >= 32u) ? (col_ - 32u) : (col_ + 64u);               \
        }                                                                      \
    }

    auto step = [&](float P, float Tt, float E) -> float {
        // --- precompute (state-independent filler for the dep-chain stalls) ---
        const float RAIN = (Tt >= TT) ? P : 0.0f;
        const float SNOW = P - RAIN;
        const float mc = fmaxf(fmaf(CFMAX, Tt, nCFMAX_TT), 0.0f);      // melt cap
        const float rc = fmaxf(fmaf(nCFRCFMAX, Tt, CFRCFMAX_TT), 0.0f);// refreeze cap
        const float Pe = E * invLPFC;

        // --- snow routine ---
        SP += SNOW;
        const float melt = fminf(mc, SP);
        MW += melt;
        SP -= melt;
        const float refr = fminf(rc, MW);
        SP += refr;
        MW -= refr;
        const float cw = CWH * SP;
        const float ts = fmaxf(MW - cw, 0.0f);
        MW = fminf(MW, cw);                               // == MW - ts

        // --- soil routine ---
        const float lg = __builtin_amdgcn_logf(SM);       // log2(SM); SM >= 1e-5
        const float bl = fminf(fmaf(BETA, lg, nBLFC), 0.0f);  // BETA*log2(SM/FC), clamped
        const float sw = __builtin_amdgcn_exp2f(bl);      // == clip((SM/FC)^BETA, 0, 1)
        const float rt = RAIN + ts;
        const float rg = rt * sw;
        SM = SM + rt - rg;
        const float ex = fmaxf(SM - FC, 0.0f);
        SM = fminf(SM, FC);                               // == SM - ex
        const float et = fminf(fminf(SM, SM * Pe), E);    // min3; Pe = PET/(LP*FC)
        SM = fmaxf(SM - et, 1e-5f);

        // --- response routine (Q0+Q1 == s2 - s4) ---
        SUZ = SUZ + rg + ex;
        const float pc = fminf(SUZ, PERCc);
        const float s2 = fmaxf(SUZ - PERCc, 0.0f);        // == SUZ - pc
        const float s3 = fminf(s2, fmaf(OMK0, s2, K0UZL));// == s2 - K0*max(s2-UZL,0)
        const float s4 = s3 * OMK1;                       // == s3 - Q1
        SUZ = s4;
        const float sl = SLZ + pc;
        const float q2 = K2 * sl;
        SLZ = sl * OMK2;                                  // == sl - q2
        return (s2 - s4) + q2;                            // Q0 + Q1 + Q2
    };

    // --- pipeline: buf[c&1] computed while buf[(c+1)&1] streams in ---
    ISSUE_CHUNK(0, 0)

    char* ob = (char*)out;
    uint32_t ooff = (uint32_t)(g * NM + m) * 4u;
    const uint32_t ostep = (uint32_t)(G * NM) * 4u;

    int c = 0;
    for (int cs = 0; cs < T; cs += TCH, ++c) {
        const int nb = c & 1;
        if (cs + TCH < T) {
            ISSUE_CHUNK(cs + TCH, nb ^ 1)
            // newest 12 outstanding VMEM = next chunk's copies; waiting to <=12
            // guarantees THIS chunk's copies (and older stores) retired.
            asm volatile("s_waitcnt vmcnt(12)" ::: "memory");
        } else {
            asm volatile("s_waitcnt vmcnt(0)" ::: "memory");
        }

        const int tcnt = (T - cs < TCH) ? (T - cs) : TCH;
        const float* L = &lds[nb][gl * 3];   // 12B/step; offsets {0,3..21}%32: conflict-free
        if (tcnt == TCH) {
            // Full chunk: batch BATCH steps' LDS reads into registers up front
            // (24 independent ds_reads pipeline; latency amortized 8x), then run
            // the dependent recurrence on register-resident forcing.
            for (int tt = 0; tt < TCH; tt += BATCH) {
                float Pv[BATCH], Tv[BATCH], Ev[BATCH];
                #pragma unroll
                for (int k = 0; k < BATCH; ++k) {
                    Pv[k] = L[k * 24 + 0];
                    Tv[k] = L[k * 24 + 1];
                    Ev[k] = L[k * 24 + 2];
                }
                L += BATCH * 24;
                #pragma unroll
                for (int k = 0; k < BATCH; ++k) {
                    const float Q = step(Pv[k], Tv[k], Ev[k]);
                    *(float*)(ob + ooff) = Q;    // 64 consecutive floats/wave: coalesced
                    ooff += ostep;
                }
            }
        } else {
            // Final partial chunk (<= TCH-1 steps): simple per-step path.
            for (int tt = 0; tt < tcnt; ++tt) {
                const float P = L[0], Tt = L[1], E = L[2];
                L += 24;
                const float Q = step(P, Tt, E);
                *(float*)(ob + ooff) = Q;
                ooff += ostep;
            }
        }
    }
    #undef ISSUE_CHUNK
}

extern "C" void kernel_launch(void* const* d_in, const int* in_sizes, int n_in,
                              void* d_out, int out_size, void* d_ws, size_t ws_size,
                              hipStream_t stream) {
    const float* x    = (const float*)d_in[0];   // [T, G, 3]
    const float* praw = (const float*)d_in[1];   // [1, G, 12, 8]
    float* out = (float*)d_out;                  // [T, G, 8]

    const int G = in_sizes[1] / (NPAR * NM);     // 4000
    const int T = in_sizes[0] / (3 * G);         // 730

    const int grid = G / 8;                      // 500 single-wave blocks (G % 8 == 0)
    hbv_kernel<<<grid, 64, 0, stream>>>(x, praw, out, G, T);
}

// Round 10
// 81.262 us; speedup vs baseline: 1.0939x; 1.0939x over previous
//
#include <hip/hip_runtime.h>
#include <math.h>
#include <stdint.h>

#define NM 8          // nmul
#define NPAR 12
#define KS 32         // timesteps per pipeline round (= forcing chunk)
#define NLL 3         // 1KB global_load_lds ops per forcing chunk (KS*96/1024)

typedef __attribute__((address_space(1))) const void gv_t;
typedef __attribute__((address_space(3))) void lv_t;

// Block = 128 threads = 2 waves, 64 chains (8 g x 8 m).
// Wave 0 (producer): forcing staging + snow routine (SP, MW) -> relays (rt, E).
// Wave 1 (consumer): soil + response (SM, SUZ, SLZ) -> stores Q. One round behind.
__global__ __launch_bounds__(128, 1) void hbv_kernel(
    const float* __restrict__ x,      // [T, G, 3]  (prcp, tmean, pet)
    const float* __restrict__ praw,   // [1, G, 12, NM] in [0,1)
    float* __restrict__ out,          // [T, G, NM]
    int G, int T)
{
    __shared__ float  fbuf[2][KS * 24];     // forcing chunks (producer only), 6 KB
    __shared__ float2 ring[2][KS][64];      // (rt, E) relay producer->consumer, 32 KB

    const int wid  = threadIdx.x >> 6;      // wave id: 0 producer, 1 consumer
    const int lane = threadIdx.x & 63;
    const int b    = blockIdx.x;
    const int g0   = b << 3;
    const int gl   = lane >> 3;             // g within block
    const int m    = lane & 7;
    const int g    = g0 + gl;

    // Parameter bounds: BETA, FC, K0, K1, K2, LP, PERC, UZL, TT, CFMAX, CFR, CWH
    const float lb[NPAR] = {1.0f, 50.0f, 0.05f, 0.01f, 0.001f, 0.2f, 0.0f, 0.0f, -2.5f, 0.5f, 0.0f, 0.0f};
    const float ub[NPAR] = {6.0f, 1000.0f, 0.9f, 0.5f, 0.2f, 1.0f, 10.0f, 100.0f, 2.5f, 10.0f, 0.1f, 0.2f};

    float p[NPAR];
    const float* pr = praw + (size_t)g * (NPAR * NM) + m;
    #pragma unroll
    for (int i = 0; i < NPAR; ++i) p[i] = pr[i * NM] * (ub[i] - lb[i]) + lb[i];

    const int NBLK = (T + KS - 1) / KS;     // 23 rounds of work

    if (wid == 0) {
        // ------------------------- PRODUCER (snow) -------------------------
        const float TT = p[8], CFMAX = p[9], CFR = p[10], CWH = p[11];
        const float nCFMAX_TT   = -(CFMAX * TT);
        const float nCFRCFMAX   = -(CFR * CFMAX);
        const float CFRCFMAX_TT = (CFR * CFMAX) * TT;

        float SP = 0.001f, MW = 0.001f;

        // forcing chunk-copy geometry (16B-aligned: 96 = 6*16, G*12 = 48000)
        const char* xb = (const char*)x;
        const uint32_t xstep  = (uint32_t)G * 12u;
        const uint32_t gbase  = (uint32_t)g0 * 12u;
        const uint32_t lin    = (uint32_t)lane * 16u;
        const uint32_t r0     = lin / 96u;
        const uint32_t c0     = lin % 96u;          // in {0,16,32,48,64,80}
        const uint32_t rowmax = (uint32_t)(T - 1);

        #define ISSUE_CHUNK(cs_, nb_)                                          \
        {                                                                      \
            uint32_t row_ = (uint32_t)(cs_) + r0;                              \
            uint32_t col_ = c0;                                                \
            _Pragma("unroll")                                                  \
            for (int i_ = 0; i_ < NLL; ++i_) {                                 \
                const uint32_t rg_ = row_ < rowmax ? row_ : rowmax;            \
                const uint32_t go_ = rg_ * xstep + gbase + col_;               \
                __builtin_amdgcn_global_load_lds((gv_t*)(xb + go_),            \
                    (lv_t*)&fbuf[nb_][i_ * 256], 16, 0, 0);                    \
                /* +1024B = 10 rows + 64B within the 96B-row raster */         \
                row_ += 10u + (col_ >= 32u ? 1u : 0u);                         \
                col_  = (col_ >= 32u) ? (col_ - 32u) : (col_ + 64u);           \
            }                                                                  \
        }

        ISSUE_CHUNK(0, 0)

        for (int r = 0; r <= NBLK; ++r) {
            if (r < NBLK) {
                if (r + 1 < NBLK) {
                    ISSUE_CHUNK((r + 1) * KS, (r + 1) & 1)
                    // newest 3 outstanding = next chunk; <=3 left means THIS
                    // chunk's copies have retired.
                    asm volatile("s_waitcnt vmcnt(3)" ::: "memory");
                } else {
                    asm volatile("s_waitcnt vmcnt(0)" ::: "memory");
                }
                const int cnt = (T - r * KS < KS) ? (T - r * KS) : KS;
                const float*  F = &fbuf[r & 1][gl * 3];
                float2*       R = &ring[r & 1][0][lane];
                #pragma unroll 4
                for (int tt = 0; tt < cnt; ++tt) {
                    const float P = F[0], Tt = F[1], E = F[2];
                    F += 24;
                    const float RAIN = (Tt >= TT) ? P : 0.0f;
                    const float SNOW = P - RAIN;
                    const float mc = fmaxf(fmaf(CFMAX, Tt, nCFMAX_TT), 0.0f);
                    const float rc = fmaxf(fmaf(nCFRCFMAX, Tt, CFRCFMAX_TT), 0.0f);
                    SP += SNOW;
                    const float melt = fminf(mc, SP);
                    MW += melt;
                    SP -= melt;
                    const float refr = fminf(rc, MW);
                    SP += refr;
                    MW -= refr;
                    const float cw = CWH * SP;
                    const float ts = fmaxf(MW - cw, 0.0f);
                    MW = fminf(MW, cw);                     // == MW - ts
                    float2 rel; rel.x = RAIN + ts; rel.y = E;
                    *R = rel;                               // ds_write_b64
                    R += 64;
                }
            }
            __syncthreads();
        }
        #undef ISSUE_CHUNK
    } else {
        // --------------------- CONSUMER (soil + response) ---------------------
        const float BETA = p[0], FC = p[1], K0 = p[2], K1 = p[3], K2 = p[4],
                    LP = p[5], PERCc = p[6], UZL = p[7];
        const float invLPFC = 1.0f / (LP * FC);
        const float nBLFC   = -BETA * __builtin_amdgcn_logf(FC);  // -BETA*log2(FC)
        const float OMK0    = 1.0f - K0;
        const float K0UZL   = K0 * UZL;
        const float OMK1    = 1.0f - K1;
        const float OMK2    = 1.0f - K2;

        float SM = 0.001f, SUZ = 0.001f, SLZ = 0.001f;

        char* ob = (char*)out;
        uint32_t ooff = (uint32_t)(g * NM + m) * 4u;
        const uint32_t ostep = (uint32_t)(G * NM) * 4u;

        for (int r = 0; r <= NBLK; ++r) {
            if (r >= 1) {
                const int base = (r - 1) * KS;
                const int cnt  = (T - base < KS) ? (T - base) : KS;
                const float2* R = &ring[(r - 1) & 1][0][lane];
                #pragma unroll 4
                for (int tt = 0; tt < cnt; ++tt) {
                    const float2 rel = *R;                  // ds_read_b64
                    R += 64;
                    const float rt = rel.x, E = rel.y;

                    // --- soil routine (verbatim R7 math) ---
                    const float lg = __builtin_amdgcn_logf(SM);
                    const float bl = fminf(fmaf(BETA, lg, nBLFC), 0.0f);
                    const float sw = __builtin_amdgcn_exp2f(bl);
                    const float rg = rt * sw;
                    SM = SM + rt - rg;
                    const float ex = fmaxf(SM - FC, 0.0f);
                    SM = fminf(SM, FC);                     // == SM - ex
                    const float Pe = E * invLPFC;
                    const float et = fminf(fminf(SM, SM * Pe), E);  // v_min3
                    SM = fmaxf(SM - et, 1e-5f);

                    // --- response routine (Q0+Q1 == s2 - s4) ---
                    SUZ = SUZ + rg + ex;
                    const float pc = fminf(SUZ, PERCc);
                    const float s2 = fmaxf(SUZ - PERCc, 0.0f);
                    const float s3 = fminf(s2, fmaf(OMK0, s2, K0UZL));
                    const float s4 = s3 * OMK1;
                    SUZ = s4;
                    const float sl = SLZ + pc;
                    const float q2 = K2 * sl;
                    SLZ = sl * OMK2;
                    const float Q = (s2 - s4) + q2;

                    *(float*)(ob + ooff) = Q;               // coalesced 256B/wave
                    ooff += ostep;
                }
            }
            __syncthreads();
        }
    }
}

extern "C" void kernel_launch(void* const* d_in, const int* in_sizes, int n_in,
                              void* d_out, int out_size, void* d_ws, size_t ws_size,
                              hipStream_t stream) {
    const float* x    = (const float*)d_in[0];   // [T, G, 3]
    const float* praw = (const float*)d_in[1];   // [1, G, 12, 8]
    float* out = (float*)d_out;                  // [T, G, 8]

    const int G = in_sizes[1] / (NPAR * NM);     // 4000
    const int T = in_sizes[0] / (3 * G);         // 730

    const int grid = G / 8;                      // 500 blocks x 2 waves = 1000 waves
    hbv_kernel<<<grid, 128, 0, stream>>>(x, praw, out, G, T);
}